// Round 3
// baseline (76.112 us; speedup 1.0000x reference)
//
#include <hip/hip_runtime.h>
#include <math.h>

#define NB 32
#define NA 3
#define NC 80
#define NH 56
#define NW 56
#define NT 50
#define HW (NH*NW)          // 3136
#define CELLS_PER_B (NA*HW) // 9408
#define CH_PER_A (5+NC)     // 85
#define EPSF 1e-7f
#define NBLK_X ((CELLS_PER_B + 255) / 256)   // 37
#define NBLK (NBLK_X * NB)                   // 1184

__device__ __forceinline__ float fsig(float v) { return 1.0f / (1.0f + __expf(-v)); }

// ---------------------------------------------------------------------------
// Single fused kernel. grid (37, 32), block 256.
// Phase 0: block-local target prep (50 targets of this batch) into LDS.
// Phase 1: dense pass — silence test + coord/conf loss; object cells -> LDS list.
// Phase 2: class focal loss, lane-parallel over classes (3 obj x 80 cls).
// Phase 3: block reduce -> global atomics -> last-block finalize.
// ---------------------------------------------------------------------------
__global__ __launch_bounds__(256) void fused_kernel(const float* __restrict__ out,
                                                    const float* __restrict__ tb,
                                                    const float* __restrict__ tcls,
                                                    const float* __restrict__ cwt,
                                                    float* __restrict__ accum,  // [0]=main [1]=cls [2]=nsel
                                                    int* __restrict__ done,
                                                    float* __restrict__ outp) {
    __shared__ float4 sp1[NT], sp2[NT];
    __shared__ int s_obj[NT];
    __shared__ int s_cnt;
    __shared__ float redm[4], redc[4];

    const int b = blockIdx.y;
    const int tid = threadIdx.x;

    const float aw[3] = {1.28967f, 2.12714f, 3.27212f};
    const float ah[3] = {4.15014f, 5.09344f, 5.87423f};
    const float law[3] = {0.25438842f, 0.75477730f, 1.18543813f};   // ln(aw)
    const float lah[3] = {1.42314173f, 1.62795138f, 1.77057764f};   // ln(ah)

    // ---- Phase 0: prep this batch's targets into LDS ----
    if (tid == 0) s_cnt = 0;
    if (tid < NT) {
        float4 box = ((const float4*)tb)[b * NT + tid];
        float gx = box.x * (float)NW;
        float gy = box.y * (float)NH;
        float gw = box.z * (float)NW;
        float gh = box.w * (float)NH;
        if (box.z > 0.0f) {
            sp1[tid] = make_float4(gx - 0.5f * gw, gx + 0.5f * gw,
                                   gy - 0.5f * gh, gy + 0.5f * gh);
            int bn = 0;
            float best = -1.0f;
            #pragma unroll
            for (int k = 0; k < 3; ++k) {
                float inter = fminf(aw[k], gw) * fminf(ah[k], gh);
                float uni = aw[k] * ah[k] + gw * gh - inter;
                float r = inter / uni;
                if (r > best) { best = r; bn = k; }
            }
            int gi = (int)gx; gi = gi < 0 ? 0 : (gi > NW - 1 ? NW - 1 : gi);
            int gj = (int)gy; gj = gj < 0 ? 0 : (gj > NH - 1 ? NH - 1 : gj);
            int flat_local = (bn * NH + gj) * NW + gi;
            sp2[tid] = make_float4(gw, gh, 0.6f * gw * gh, __int_as_float(flat_local));
        } else {
            sp1[tid] = make_float4(1e9f, 1e9f, 1e9f, 1e9f);
            sp2[tid] = make_float4(0.0f, 0.0f, 0.0f, __int_as_float(-1));
        }
    }
    __syncthreads();

    // ---- Phase 1: dense pass ----
    const int lc = blockIdx.x * blockDim.x + tid;
    float lmain = 0.0f;

    if (lc < CELLS_PER_B) {
        const int a = lc / HW;
        const int rem = lc - a * HW;
        const int j = rem / NW;
        const int i = rem - j * NW;

        const float* base = out + (size_t)b * (NA * CH_PER_A * HW) + (size_t)(a * CH_PER_A) * HW + rem;
        float o0 = base[0];
        float o1 = base[HW];
        float o2 = base[2 * HW];
        float o3 = base[3 * HW];
        float o4 = base[4 * HW];

        float x = fsig(o0);
        float y = fsig(o1);
        float conf = fsig(o4);
        float pw = __expf(o2) * aw[a];
        float ph = __expf(o3) * ah[a];
        float px = x + (float)i;
        float py = y + (float)j;
        float px1 = px - 0.5f * pw, px2 = px + 0.5f * pw;
        float py1 = py - 0.5f * ph, py2 = py + 0.5f * ph;
        float parea06 = 0.6f * (pw * ph);

        bool sil = false;
        int tsel = -1;
        #pragma unroll 5
        for (int t = 0; t < NT; ++t) {
            float4 p1 = sp1[t];
            float4 p2 = sp2[t];
            float mx = fminf(p1.x, px1);
            float Mx = fmaxf(p1.y, px2);
            float my = fminf(p1.z, py1);
            float My = fmaxf(p1.w, py2);
            float cw = (p2.x + pw) - (Mx - mx);
            float ch = (p2.y + ph) - (My - my);
            float inter = fmaxf(cw, 0.0f) * fmaxf(ch, 0.0f);
            // iou>0.6  <=>  1.6*inter > 0.6*(areaA+areaP)
            sil = sil || (1.6f * inter > (p2.z + parea06));
            if (__float_as_int(p2.w) == lc) tsel = t;   // last t wins (matches .at[].set)
        }

        if (tsel >= 0) {
            float4 g1 = sp1[tsel];
            float4 g2 = sp2[tsel];
            float gx = 0.5f * (g1.x + g1.y);
            float gy = 0.5f * (g1.z + g1.w);
            float tx = gx - (float)i;
            float ty = gy - (float)j;
            float tw = __logf(g2.x) - law[a];
            float th = __logf(g2.y) - lah[a];
            lmain += 0.5f * ((x - tx) * (x - tx) + (y - ty) * (y - ty) +
                             (o2 - tw) * (o2 - tw) + (o3 - th) * (o3 - th));
            float mx = fminf(g1.x, px1), Mx = fmaxf(g1.y, px2);
            float my = fminf(g1.z, py1), My = fmaxf(g1.w, py2);
            float cw = (g2.x + pw) - (Mx - mx);
            float ch = (g2.y + ph) - (My - my);
            float inter = fmaxf(cw, 0.0f) * fmaxf(ch, 0.0f);
            float uni = g2.x * g2.y + (pw * ph) - inter;
            float tconf = inter / uni;
            lmain += 2.5f * (conf - tconf) * (conf - tconf);   // 0.5*OBJECT_SCALE

            int pos = atomicAdd(&s_cnt, 1);
            s_obj[pos] = (lc << 6) | tsel;                      // pack
        } else {
            lmain += sil ? 0.0f : 0.5f * conf * conf;
        }
    }
    __syncthreads();

    // ---- Phase 2: class loss, 3 objects x 80 classes per pass ----
    const int cnt = s_cnt;
    float lcls = 0.0f;
    if (cnt > 0) {
        const int oo = tid / NC;        // 0..3 (only <3 used)
        const int c = tid - oo * NC;    // class index
        if (oo < 3) {
            float w = cwt[c];
            float ew1 = __expf(w);
            float ew0 = __expf(1.0f - w);
            for (int o0 = 0; o0 < cnt; o0 += 3) {
                int o = o0 + oo;
                if (o < cnt) {
                    int pk = s_obj[o];
                    int olc = pk >> 6;
                    int tsel = pk & 63;
                    int a = olc / HW;
                    int rem = olc - a * HW;
                    float p = fsig(out[(size_t)b * (NA * CH_PER_A * HW) +
                                       (size_t)(a * CH_PER_A + 5 + c) * HW + rem]);
                    float t = tcls[(size_t)(b * NT + tsel) * NC + c];
                    float l1 = sqrtf(1.0f - p + EPSF) * __logf(p + EPSF) * ew1;
                    float l0 = sqrtf(p + EPSF) * __logf(1.0f - p + EPSF) * ew0;
                    lcls += t * l1 + (1.0f - t) * l0;
                }
            }
        }
    }

    // ---- Phase 3: block reduction + global atomics + last-block finalize ----
    for (int off = 32; off > 0; off >>= 1) {
        lmain += __shfl_down(lmain, off, 64);
        lcls  += __shfl_down(lcls, off, 64);
    }
    if ((tid & 63) == 0) { redm[tid >> 6] = lmain; redc[tid >> 6] = lcls; }
    __syncthreads();
    if (tid == 0) {
        float m = redm[0] + redm[1] + redm[2] + redm[3];
        float c = redc[0] + redc[1] + redc[2] + redc[3];
        atomicAdd(&accum[0], m);
        atomicAdd(&accum[1], c);
        atomicAdd(&accum[2], (float)cnt);
        __threadfence();
        int old = atomicAdd(done, 1);
        if (old == NBLK - 1) {
            // all blocks' accum atomics are complete and visible
            float ms = atomicAdd(&accum[0], 0.0f);
            float cs = atomicAdd(&accum[1], 0.0f);
            float ns = atomicAdd(&accum[2], 0.0f);
            float nsel = fmaxf(ns, 1.0f);
            outp[0] = ms - cs / nsel;
        }
    }
}

extern "C" void kernel_launch(void* const* d_in, const int* in_sizes, int n_in,
                              void* d_out, int out_size, void* d_ws, size_t ws_size,
                              hipStream_t stream) {
    const float* output = (const float*)d_in[0];
    const float* tb     = (const float*)d_in[1];
    const float* tcls   = (const float*)d_in[2];
    const float* cwt    = (const float*)d_in[3];

    float* accum = (float*)d_ws;            // 3 floats
    int*   done  = (int*)((char*)d_ws + 12);

    hipMemsetAsync(d_ws, 0, 16, stream);    // zero accum + done (graph-capturable)
    fused_kernel<<<dim3(NBLK_X, NB), 256, 0, stream>>>(
        output, tb, tcls, cwt, accum, done, (float*)d_out);
}

// Round 4
// 20.952 us; speedup vs baseline: 3.6328x; 3.6328x over previous
//
#include <hip/hip_runtime.h>
#include <math.h>

#define NB 32
#define NA 3
#define NC 80
#define NH 56
#define NW 56
#define NT 50
#define HW (NH*NW)          // 3136
#define CELLS_PER_B (NA*HW) // 9408
#define CH_PER_A (5+NC)     // 85
#define EPSF 1e-7f
#define NBLK_X ((CELLS_PER_B + 255) / 256)   // 37
#define NBLK (NBLK_X * NB)                   // 1184

__device__ __forceinline__ float fsig(float v) { return 1.0f / (1.0f + __expf(-v)); }

// ---------------------------------------------------------------------------
// Fused kernel. grid (37, 32), block 256.
// Phase 0: block-local target prep (50 targets of this batch) into LDS.
// Phase 1: dense pass — silence test + coord/conf loss; object cells -> LDS list.
// Phase 2: class focal loss, lane-parallel over classes (3 obj x 80 cls).
// Phase 3: block reduce -> ONE float4 partial store per block (no atomics).
// ---------------------------------------------------------------------------
__global__ __launch_bounds__(256) void fused_kernel(const float* __restrict__ out,
                                                    const float* __restrict__ tb,
                                                    const float* __restrict__ tcls,
                                                    const float* __restrict__ cwt,
                                                    float4* __restrict__ part) {
    __shared__ float4 sp1[NT], sp2[NT];
    __shared__ int s_obj[NT];
    __shared__ int s_cnt;
    __shared__ float redm[4], redc[4];

    const int b = blockIdx.y;
    const int tid = threadIdx.x;

    const float aw[3] = {1.28967f, 2.12714f, 3.27212f};
    const float ah[3] = {4.15014f, 5.09344f, 5.87423f};
    const float law[3] = {0.25438842f, 0.75477730f, 1.18543813f};   // ln(aw)
    const float lah[3] = {1.42314173f, 1.62795138f, 1.77057764f};   // ln(ah)

    // ---- Phase 0: prep this batch's targets into LDS ----
    if (tid == 0) s_cnt = 0;
    if (tid < NT) {
        float4 box = ((const float4*)tb)[b * NT + tid];
        float gx = box.x * (float)NW;
        float gy = box.y * (float)NH;
        float gw = box.z * (float)NW;
        float gh = box.w * (float)NH;
        if (box.z > 0.0f) {
            sp1[tid] = make_float4(gx - 0.5f * gw, gx + 0.5f * gw,
                                   gy - 0.5f * gh, gy + 0.5f * gh);
            int bn = 0;
            float best = -1.0f;
            #pragma unroll
            for (int k = 0; k < 3; ++k) {
                float inter = fminf(aw[k], gw) * fminf(ah[k], gh);
                float uni = aw[k] * ah[k] + gw * gh - inter;
                float r = inter / uni;
                if (r > best) { best = r; bn = k; }
            }
            int gi = (int)gx; gi = gi < 0 ? 0 : (gi > NW - 1 ? NW - 1 : gi);
            int gj = (int)gy; gj = gj < 0 ? 0 : (gj > NH - 1 ? NH - 1 : gj);
            int flat_local = (bn * NH + gj) * NW + gi;
            sp2[tid] = make_float4(gw, gh, 0.6f * gw * gh, __int_as_float(flat_local));
        } else {
            sp1[tid] = make_float4(1e9f, 1e9f, 1e9f, 1e9f);
            sp2[tid] = make_float4(0.0f, 0.0f, 0.0f, __int_as_float(-1));
        }
    }
    __syncthreads();

    // ---- Phase 1: dense pass ----
    const int lc = blockIdx.x * blockDim.x + tid;
    float lmain = 0.0f;

    if (lc < CELLS_PER_B) {
        const int a = lc / HW;
        const int rem = lc - a * HW;
        const int j = rem / NW;
        const int i = rem - j * NW;

        const float* base = out + (size_t)b * (NA * CH_PER_A * HW) + (size_t)(a * CH_PER_A) * HW + rem;
        float o0 = base[0];
        float o1 = base[HW];
        float o2 = base[2 * HW];
        float o3 = base[3 * HW];
        float o4 = base[4 * HW];

        float x = fsig(o0);
        float y = fsig(o1);
        float conf = fsig(o4);
        float pw = __expf(o2) * aw[a];
        float ph = __expf(o3) * ah[a];
        float px = x + (float)i;
        float py = y + (float)j;
        float px1 = px - 0.5f * pw, px2 = px + 0.5f * pw;
        float py1 = py - 0.5f * ph, py2 = py + 0.5f * ph;
        float parea06 = 0.6f * (pw * ph);

        bool sil = false;
        int tsel = -1;
        #pragma unroll 5
        for (int t = 0; t < NT; ++t) {
            float4 p1 = sp1[t];
            float4 p2 = sp2[t];
            float mx = fminf(p1.x, px1);
            float Mx = fmaxf(p1.y, px2);
            float my = fminf(p1.z, py1);
            float My = fmaxf(p1.w, py2);
            float cw = (p2.x + pw) - (Mx - mx);
            float ch = (p2.y + ph) - (My - my);
            float inter = fmaxf(cw, 0.0f) * fmaxf(ch, 0.0f);
            // iou>0.6  <=>  1.6*inter > 0.6*(areaA+areaP)
            sil = sil || (1.6f * inter > (p2.z + parea06));
            if (__float_as_int(p2.w) == lc) tsel = t;   // last t wins (matches .at[].set)
        }

        if (tsel >= 0) {
            float4 g1 = sp1[tsel];
            float4 g2 = sp2[tsel];
            float gx = 0.5f * (g1.x + g1.y);
            float gy = 0.5f * (g1.z + g1.w);
            float tx = gx - (float)i;
            float ty = gy - (float)j;
            float tw = __logf(g2.x) - law[a];
            float th = __logf(g2.y) - lah[a];
            lmain += 0.5f * ((x - tx) * (x - tx) + (y - ty) * (y - ty) +
                             (o2 - tw) * (o2 - tw) + (o3 - th) * (o3 - th));
            float mx = fminf(g1.x, px1), Mx = fmaxf(g1.y, px2);
            float my = fminf(g1.z, py1), My = fmaxf(g1.w, py2);
            float cw = (g2.x + pw) - (Mx - mx);
            float ch = (g2.y + ph) - (My - my);
            float inter = fmaxf(cw, 0.0f) * fmaxf(ch, 0.0f);
            float uni = g2.x * g2.y + (pw * ph) - inter;
            float tconf = inter / uni;
            lmain += 2.5f * (conf - tconf) * (conf - tconf);   // 0.5*OBJECT_SCALE

            int pos = atomicAdd(&s_cnt, 1);                     // LDS atomic only
            s_obj[pos] = (lc << 6) | tsel;                      // pack
        } else {
            lmain += sil ? 0.0f : 0.5f * conf * conf;
        }
    }
    __syncthreads();

    // ---- Phase 2: class loss, 3 objects x 80 classes per pass ----
    const int cnt = s_cnt;
    float lcls = 0.0f;
    if (cnt > 0) {
        const int oo = tid / NC;        // 0..3 (only <3 used)
        const int c = tid - oo * NC;    // class index
        if (oo < 3) {
            float w = cwt[c];
            float ew1 = __expf(w);
            float ew0 = __expf(1.0f - w);
            for (int o0 = 0; o0 < cnt; o0 += 3) {
                int o = o0 + oo;
                if (o < cnt) {
                    int pk = s_obj[o];
                    int olc = pk >> 6;
                    int tsel = pk & 63;
                    int a = olc / HW;
                    int rem = olc - a * HW;
                    float p = fsig(out[(size_t)b * (NA * CH_PER_A * HW) +
                                       (size_t)(a * CH_PER_A + 5 + c) * HW + rem]);
                    float t = tcls[(size_t)(b * NT + tsel) * NC + c];
                    float l1 = sqrtf(1.0f - p + EPSF) * __logf(p + EPSF) * ew1;
                    float l0 = sqrtf(p + EPSF) * __logf(1.0f - p + EPSF) * ew0;
                    lcls += t * l1 + (1.0f - t) * l0;
                }
            }
        }
    }

    // ---- Phase 3: block reduction -> one float4 partial per block ----
    for (int off = 32; off > 0; off >>= 1) {
        lmain += __shfl_down(lmain, off, 64);
        lcls  += __shfl_down(lcls, off, 64);
    }
    if ((tid & 63) == 0) { redm[tid >> 6] = lmain; redc[tid >> 6] = lcls; }
    __syncthreads();
    if (tid == 0) {
        float m = redm[0] + redm[1] + redm[2] + redm[3];
        float c = redc[0] + redc[1] + redc[2] + redc[3];
        part[blockIdx.y * gridDim.x + blockIdx.x] =
            make_float4(m, c, (float)cnt, 0.0f);
    }
}

// ---------------------------------------------------------------------------
// Finalize: one block reduces the 1184 float4 partials.
// ---------------------------------------------------------------------------
__global__ __launch_bounds__(256) void finalize_kernel(const float4* __restrict__ part,
                                                       float* __restrict__ outp) {
    const int tid = threadIdx.x;
    float m = 0.0f, c = 0.0f, n = 0.0f;
    for (int i = tid; i < NBLK; i += 256) {
        float4 p = part[i];
        m += p.x; c += p.y; n += p.z;
    }
    for (int off = 32; off > 0; off >>= 1) {
        m += __shfl_down(m, off, 64);
        c += __shfl_down(c, off, 64);
        n += __shfl_down(n, off, 64);
    }
    __shared__ float rm[4], rc[4], rn[4];
    if ((tid & 63) == 0) { rm[tid >> 6] = m; rc[tid >> 6] = c; rn[tid >> 6] = n; }
    __syncthreads();
    if (tid == 0) {
        float ms = rm[0] + rm[1] + rm[2] + rm[3];
        float cs = rc[0] + rc[1] + rc[2] + rc[3];
        float ns = rn[0] + rn[1] + rn[2] + rn[3];
        float nsel = fmaxf(ns, 1.0f);
        outp[0] = ms - cs / nsel;
    }
}

extern "C" void kernel_launch(void* const* d_in, const int* in_sizes, int n_in,
                              void* d_out, int out_size, void* d_ws, size_t ws_size,
                              hipStream_t stream) {
    const float* output = (const float*)d_in[0];
    const float* tb     = (const float*)d_in[1];
    const float* tcls   = (const float*)d_in[2];
    const float* cwt    = (const float*)d_in[3];

    float4* part = (float4*)d_ws;           // NBLK * 16B = 18944 B

    fused_kernel<<<dim3(NBLK_X, NB), 256, 0, stream>>>(output, tb, tcls, cwt, part);
    finalize_kernel<<<1, 256, 0, stream>>>(part, (float*)d_out);
}